// Round 1
// baseline (130.691 us; speedup 1.0000x reference)
//
#include <hip/hip_runtime.h>

#define B_SZ 4096
#define T_SZ 200
#define IN_SZ 34
// HIDDEN = 4, 4*H = 16 gates, gate order i,f,g,o (rows of W_ih/W_hh)

__device__ __forceinline__ float sigf(float x) {
    return 1.0f / (1.0f + __expf(-x));
}
__device__ __forceinline__ float tanh_f(float x) {
    return 2.0f / (1.0f + __expf(-2.0f * x)) - 1.0f;
}

// Phase 1: x_gates[row][j][gt] = dot(x[row], W_ih[gt*4+j]) + b_ih[g] + b_hh[g]
// row = b*T + t. Permuted layout so phase 2 reads one float4 per (b,j,t).
__global__ __launch_bounds__(256) void xgates_kernel(
    const float* __restrict__ x, const float* __restrict__ W_ih,
    const float* __restrict__ b_ih, const float* __restrict__ b_hh,
    float* __restrict__ xg) {
  int row = blockIdx.x * 256 + threadIdx.x;  // exactly B*T threads launched
  float xr[IN_SZ];
  const float2* xp = reinterpret_cast<const float2*>(x + (size_t)row * IN_SZ);
  #pragma unroll
  for (int k = 0; k < IN_SZ / 2; ++k) {
    float2 v = xp[k];
    xr[2 * k] = v.x;
    xr[2 * k + 1] = v.y;
  }
  float acc[16];
  #pragma unroll
  for (int g = 0; g < 16; ++g) acc[g] = b_ih[g] + b_hh[g];  // uniform s_loads
  #pragma unroll
  for (int k = 0; k < IN_SZ; ++k) {
    #pragma unroll
    for (int g = 0; g < 16; ++g)
      acc[g] = fmaf(xr[k], W_ih[g * IN_SZ + k], acc[g]);  // W uniform -> SGPR
  }
  // write [row][j=0..3][gt=i,f,g,o] as 4 float4s (64B contiguous)
  float4* op = reinterpret_cast<float4*>(xg + (size_t)row * 16);
  #pragma unroll
  for (int j = 0; j < 4; ++j)
    op[j] = make_float4(acc[j], acc[4 + j], acc[8 + j], acc[12 + j]);
}

// Phase 2: recurrent scan. 4 lanes per batch element, lane j owns h_j/c_j and
// computes gate column j of i,f,g,o. h broadcast within the 4-lane group.
__global__ __launch_bounds__(256) void lstm_scan(
    const float* __restrict__ xg, const float* __restrict__ W_hh,
    const float* __restrict__ W_fc, const float* __restrict__ b_fc,
    float* __restrict__ out) {
  int tid = blockIdx.x * 256 + threadIdx.x;
  int b = tid >> 2;
  int j = tid & 3;
  // W_hh rows j, 4+j, 8+j, 12+j (each 4 floats), lane-resident
  float Wi[4], Wf[4], Wg[4], Wo[4];
  #pragma unroll
  for (int k = 0; k < 4; ++k) {
    Wi[k] = W_hh[(0 + j) * 4 + k];
    Wf[k] = W_hh[(4 + j) * 4 + k];
    Wg[k] = W_hh[(8 + j) * 4 + k];
    Wo[k] = W_hh[(12 + j) * 4 + k];
  }
  float h[4] = {0.f, 0.f, 0.f, 0.f};
  float c = 0.f;
  const float4* xp = reinterpret_cast<const float4*>(xg) + (size_t)b * T_SZ * 4 + j;
  int lbase = (threadIdx.x & 63) & ~3;  // group base lane within wave
  for (int t = 0; t < T_SZ; ++t) {
    float4 g4 = xp[(size_t)t * 4];
    float pi = g4.x, pf = g4.y, pg = g4.z, po = g4.w;
    #pragma unroll
    for (int k = 0; k < 4; ++k) {
      pi = fmaf(Wi[k], h[k], pi);
      pf = fmaf(Wf[k], h[k], pf);
      pg = fmaf(Wg[k], h[k], pg);
      po = fmaf(Wo[k], h[k], po);
    }
    float iv = sigf(pi);
    float fv = sigf(pf);
    float gv = tanh_f(pg);
    float ov = sigf(po);
    c = fmaf(fv, c, iv * gv);
    float hj = ov * tanh_f(c);
    h[0] = __shfl(hj, lbase + 0);
    h[1] = __shfl(hj, lbase + 1);
    h[2] = __shfl(hj, lbase + 2);
    h[3] = __shfl(hj, lbase + 3);
  }
  // final FC: out[b,cls] = b_fc[cls] + sum_k W_fc[cls,k]*h[k]; lanes 0..2 write
  if (j < 3) {
    float acc = b_fc[j];
    #pragma unroll
    for (int k = 0; k < 4; ++k) acc = fmaf(W_fc[j * 4 + k], h[k], acc);
    out[b * 3 + j] = acc;
  }
}

// Fallback (only if workspace is too small): fused single kernel, W_ih in LDS.
__global__ __launch_bounds__(256) void lstm_fused(
    const float* __restrict__ x, const float* __restrict__ W_ih,
    const float* __restrict__ W_hh, const float* __restrict__ b_ih,
    const float* __restrict__ b_hh, const float* __restrict__ W_fc,
    const float* __restrict__ b_fc, float* __restrict__ out) {
  __shared__ float Ws[16 * IN_SZ];
  for (int i = threadIdx.x; i < 16 * IN_SZ; i += 256) Ws[i] = W_ih[i];
  __syncthreads();
  int tid = blockIdx.x * 256 + threadIdx.x;
  int b = tid >> 2;
  int j = tid & 3;
  float bi = b_ih[0 + j] + b_hh[0 + j];
  float bf = b_ih[4 + j] + b_hh[4 + j];
  float bg = b_ih[8 + j] + b_hh[8 + j];
  float bo = b_ih[12 + j] + b_hh[12 + j];
  float Wi[4], Wf[4], Wg[4], Wo[4];
  #pragma unroll
  for (int k = 0; k < 4; ++k) {
    Wi[k] = W_hh[(0 + j) * 4 + k];
    Wf[k] = W_hh[(4 + j) * 4 + k];
    Wg[k] = W_hh[(8 + j) * 4 + k];
    Wo[k] = W_hh[(12 + j) * 4 + k];
  }
  float h[4] = {0.f, 0.f, 0.f, 0.f};
  float c = 0.f;
  const float2* xp = reinterpret_cast<const float2*>(x + (size_t)b * T_SZ * IN_SZ);
  int lbase = (threadIdx.x & 63) & ~3;
  for (int t = 0; t < T_SZ; ++t) {
    float xr[IN_SZ];
    #pragma unroll
    for (int k = 0; k < IN_SZ / 2; ++k) {
      float2 v = xp[(size_t)t * (IN_SZ / 2) + k];
      xr[2 * k] = v.x;
      xr[2 * k + 1] = v.y;
    }
    float pi = bi, pf = bf, pg = bg, po = bo;
    #pragma unroll
    for (int k = 0; k < IN_SZ; ++k) {
      pi = fmaf(xr[k], Ws[(0 + j) * IN_SZ + k], pi);
      pf = fmaf(xr[k], Ws[(4 + j) * IN_SZ + k], pf);
      pg = fmaf(xr[k], Ws[(8 + j) * IN_SZ + k], pg);
      po = fmaf(xr[k], Ws[(12 + j) * IN_SZ + k], po);
    }
    #pragma unroll
    for (int k = 0; k < 4; ++k) {
      pi = fmaf(Wi[k], h[k], pi);
      pf = fmaf(Wf[k], h[k], pf);
      pg = fmaf(Wg[k], h[k], pg);
      po = fmaf(Wo[k], h[k], po);
    }
    float iv = sigf(pi);
    float fv = sigf(pf);
    float gv = tanh_f(pg);
    float ov = sigf(po);
    c = fmaf(fv, c, iv * gv);
    float hj = ov * tanh_f(c);
    h[0] = __shfl(hj, lbase + 0);
    h[1] = __shfl(hj, lbase + 1);
    h[2] = __shfl(hj, lbase + 2);
    h[3] = __shfl(hj, lbase + 3);
  }
  if (j < 3) {
    float acc = b_fc[j];
    #pragma unroll
    for (int k = 0; k < 4; ++k) acc = fmaf(W_fc[j * 4 + k], h[k], acc);
    out[b * 3 + j] = acc;
  }
}

extern "C" void kernel_launch(void* const* d_in, const int* in_sizes, int n_in,
                              void* d_out, int out_size, void* d_ws, size_t ws_size,
                              hipStream_t stream) {
  const float* x    = (const float*)d_in[0];
  const float* W_ih = (const float*)d_in[1];
  const float* W_hh = (const float*)d_in[2];
  const float* b_ih = (const float*)d_in[3];
  const float* b_hh = (const float*)d_in[4];
  const float* W_fc = (const float*)d_in[5];
  const float* b_fc = (const float*)d_in[6];
  float* out = (float*)d_out;

  const size_t need = (size_t)B_SZ * T_SZ * 16 * sizeof(float);
  if (ws_size >= need) {
    float* xg = (float*)d_ws;
    hipLaunchKernelGGL(xgates_kernel, dim3(B_SZ * T_SZ / 256), dim3(256), 0, stream,
                       x, W_ih, b_ih, b_hh, xg);
    hipLaunchKernelGGL(lstm_scan, dim3(B_SZ * 4 / 256), dim3(256), 0, stream,
                       xg, W_hh, W_fc, b_fc, out);
  } else {
    hipLaunchKernelGGL(lstm_fused, dim3(B_SZ * 4 / 256), dim3(256), 0, stream,
                       x, W_ih, W_hh, b_ih, b_hh, W_fc, b_fc, out);
  }
}

// Round 2
// 98.975 us; speedup vs baseline: 1.3204x; 1.3204x over previous
//
#include <hip/hip_runtime.h>

#define B_SZ 4096
#define T_SZ 200
#define IN_SZ 34
// HIDDEN = 4, 4*H = 16 gates, gate order i,f,g,o (rows of W_ih/W_hh)

__device__ __forceinline__ float sigf(float x) {
    return 1.0f / (1.0f + __expf(-x));
}
__device__ __forceinline__ float tanh_f(float x) {
    return 2.0f / (1.0f + __expf(-2.0f * x)) - 1.0f;
}

// broadcast lane L (0..3) of each quad to all 4 lanes of the quad via DPP
__device__ __forceinline__ float quad_bcast0(float v) {
    int s = __float_as_int(v);
    return __int_as_float(__builtin_amdgcn_update_dpp(s, s, 0x00, 0xf, 0xf, true));
}
__device__ __forceinline__ float quad_bcast1(float v) {
    int s = __float_as_int(v);
    return __int_as_float(__builtin_amdgcn_update_dpp(s, s, 0x55, 0xf, 0xf, true));
}
__device__ __forceinline__ float quad_bcast2(float v) {
    int s = __float_as_int(v);
    return __int_as_float(__builtin_amdgcn_update_dpp(s, s, 0xAA, 0xf, 0xf, true));
}
__device__ __forceinline__ float quad_bcast3(float v) {
    int s = __float_as_int(v);
    return __int_as_float(__builtin_amdgcn_update_dpp(s, s, 0xFF, 0xf, 0xf, true));
}

// Phase 1: x_gates[row][j][gt] = dot(x[row], W_ih[gt*4+j]) + b_ih[g] + b_hh[g]
// row = b*T + t. LDS-staged so global reads are perfectly coalesced float4.
__global__ __launch_bounds__(256) void xgates_kernel(
    const float* __restrict__ x, const float* __restrict__ W_ih,
    const float* __restrict__ b_ih, const float* __restrict__ b_hh,
    float* __restrict__ xg) {
  __shared__ float xs[256 * IN_SZ];  // 34,816 B
  // Stage 256 rows (256*34 floats = 2176 float4) contiguously.
  const float4* src = reinterpret_cast<const float4*>(x + (size_t)blockIdx.x * 256 * IN_SZ);
  float4* dst = reinterpret_cast<float4*>(xs);
  for (int i = threadIdx.x; i < 256 * IN_SZ / 4; i += 256) dst[i] = src[i];
  __syncthreads();

  // Row -> registers via ds_read_b64 (8B-aligned, 2-way bank alias = free)
  float xr[IN_SZ];
  const float2* rp = reinterpret_cast<const float2*>(&xs[threadIdx.x * IN_SZ]);
  #pragma unroll
  for (int k = 0; k < IN_SZ / 2; ++k) {
    float2 v = rp[k];
    xr[2 * k] = v.x;
    xr[2 * k + 1] = v.y;
  }
  float acc[16];
  #pragma unroll
  for (int g = 0; g < 16; ++g) acc[g] = b_ih[g] + b_hh[g];  // uniform s_loads
  #pragma unroll
  for (int k = 0; k < IN_SZ; ++k) {
    #pragma unroll
    for (int g = 0; g < 16; ++g)
      acc[g] = fmaf(xr[k], W_ih[g * IN_SZ + k], acc[g]);  // W uniform -> SGPR
  }
  // write [row][j=0..3][gt=i,f,g,o] as 4 float4s (64B contiguous per row)
  size_t row = (size_t)blockIdx.x * 256 + threadIdx.x;
  float4* op = reinterpret_cast<float4*>(xg + row * 16);
  #pragma unroll
  for (int j = 0; j < 4; ++j)
    op[j] = make_float4(acc[j], acc[4 + j], acc[8 + j], acc[12 + j]);
}

// Phase 2: recurrent scan. 4 lanes per batch element, lane j owns h_j/c_j.
// Register double-buffered prefetch (U=10), DPP quad broadcasts for h.
#define U_SZ 10
__global__ __launch_bounds__(64) void lstm_scan(
    const float* __restrict__ xg, const float* __restrict__ W_hh,
    const float* __restrict__ W_fc, const float* __restrict__ b_fc,
    float* __restrict__ out) {
  int tid = blockIdx.x * 64 + threadIdx.x;
  int b = tid >> 2;
  int j = tid & 3;
  float Wi[4], Wf[4], Wg[4], Wo[4];
  #pragma unroll
  for (int k = 0; k < 4; ++k) {
    Wi[k] = W_hh[(0 + j) * 4 + k];
    Wf[k] = W_hh[(4 + j) * 4 + k];
    Wg[k] = W_hh[(8 + j) * 4 + k];
    Wo[k] = W_hh[(12 + j) * 4 + k];
  }
  float h[4] = {0.f, 0.f, 0.f, 0.f};
  float c = 0.f;

  auto step = [&](float4 g4) {
    float pi = g4.x, pf = g4.y, pg = g4.z, po = g4.w;
    #pragma unroll
    for (int k = 0; k < 4; ++k) {
      pi = fmaf(Wi[k], h[k], pi);
      pf = fmaf(Wf[k], h[k], pf);
      pg = fmaf(Wg[k], h[k], pg);
      po = fmaf(Wo[k], h[k], po);
    }
    float iv = sigf(pi);
    float fv = sigf(pf);
    float gv = tanh_f(pg);
    float ov = sigf(po);
    c = fmaf(fv, c, iv * gv);
    float hj = ov * tanh_f(c);
    h[0] = quad_bcast0(hj);
    h[1] = quad_bcast1(hj);
    h[2] = quad_bcast2(hj);
    h[3] = quad_bcast3(hj);
  };

  const float4* xp = reinterpret_cast<const float4*>(xg) + (size_t)b * (T_SZ * 4) + j;
  float4 bufA[U_SZ], bufB[U_SZ];
  #pragma unroll
  for (int u = 0; u < U_SZ; ++u) bufA[u] = xp[4 * u];

  // T=200 = 20 blocks of 10; ping-pong pairs
  #pragma unroll 1
  for (int blk = 0; blk < 20; blk += 2) {
    const float4* p1 = xp + (size_t)(blk + 1) * (4 * U_SZ);
    #pragma unroll
    for (int u = 0; u < U_SZ; ++u) bufB[u] = p1[4 * u];
    #pragma unroll
    for (int u = 0; u < U_SZ; ++u) step(bufA[u]);
    if (blk + 2 < 20) {
      const float4* p2 = xp + (size_t)(blk + 2) * (4 * U_SZ);
      #pragma unroll
      for (int u = 0; u < U_SZ; ++u) bufA[u] = p2[4 * u];
    }
    #pragma unroll
    for (int u = 0; u < U_SZ; ++u) step(bufB[u]);
  }

  if (j < 3) {
    float acc = b_fc[j];
    #pragma unroll
    for (int k = 0; k < 4; ++k) acc = fmaf(W_fc[j * 4 + k], h[k], acc);
    out[b * 3 + j] = acc;
  }
}

// Fallback (only if workspace is too small): fused single kernel, W_ih in LDS.
__global__ __launch_bounds__(256) void lstm_fused(
    const float* __restrict__ x, const float* __restrict__ W_ih,
    const float* __restrict__ W_hh, const float* __restrict__ b_ih,
    const float* __restrict__ b_hh, const float* __restrict__ W_fc,
    const float* __restrict__ b_fc, float* __restrict__ out) {
  __shared__ float Ws[16 * IN_SZ];
  for (int i = threadIdx.x; i < 16 * IN_SZ; i += 256) Ws[i] = W_ih[i];
  __syncthreads();
  int tid = blockIdx.x * 256 + threadIdx.x;
  int b = tid >> 2;
  int j = tid & 3;
  float bi = b_ih[0 + j] + b_hh[0 + j];
  float bf = b_ih[4 + j] + b_hh[4 + j];
  float bg = b_ih[8 + j] + b_hh[8 + j];
  float bo = b_ih[12 + j] + b_hh[12 + j];
  float Wi[4], Wf[4], Wg[4], Wo[4];
  #pragma unroll
  for (int k = 0; k < 4; ++k) {
    Wi[k] = W_hh[(0 + j) * 4 + k];
    Wf[k] = W_hh[(4 + j) * 4 + k];
    Wg[k] = W_hh[(8 + j) * 4 + k];
    Wo[k] = W_hh[(12 + j) * 4 + k];
  }
  float h[4] = {0.f, 0.f, 0.f, 0.f};
  float c = 0.f;
  const float2* xp = reinterpret_cast<const float2*>(x + (size_t)b * T_SZ * IN_SZ);
  int lbase = (threadIdx.x & 63) & ~3;
  for (int t = 0; t < T_SZ; ++t) {
    float xr[IN_SZ];
    #pragma unroll
    for (int k = 0; k < IN_SZ / 2; ++k) {
      float2 v = xp[(size_t)t * (IN_SZ / 2) + k];
      xr[2 * k] = v.x;
      xr[2 * k + 1] = v.y;
    }
    float pi = bi, pf = bf, pg = bg, po = bo;
    #pragma unroll
    for (int k = 0; k < IN_SZ; ++k) {
      pi = fmaf(xr[k], Ws[(0 + j) * IN_SZ + k], pi);
      pf = fmaf(xr[k], Ws[(4 + j) * IN_SZ + k], pf);
      pg = fmaf(xr[k], Ws[(8 + j) * IN_SZ + k], pg);
      po = fmaf(xr[k], Ws[(12 + j) * IN_SZ + k], po);
    }
    #pragma unroll
    for (int k = 0; k < 4; ++k) {
      pi = fmaf(Wi[k], h[k], pi);
      pf = fmaf(Wf[k], h[k], pf);
      pg = fmaf(Wg[k], h[k], pg);
      po = fmaf(Wo[k], h[k], po);
    }
    float iv = sigf(pi);
    float fv = sigf(pf);
    float gv = tanh_f(pg);
    float ov = sigf(po);
    c = fmaf(fv, c, iv * gv);
    float hj = ov * tanh_f(c);
    h[0] = __shfl(hj, lbase + 0);
    h[1] = __shfl(hj, lbase + 1);
    h[2] = __shfl(hj, lbase + 2);
    h[3] = __shfl(hj, lbase + 3);
  }
  if (j < 3) {
    float acc = b_fc[j];
    #pragma unroll
    for (int k = 0; k < 4; ++k) acc = fmaf(W_fc[j * 4 + k], h[k], acc);
    out[b * 3 + j] = acc;
  }
}

extern "C" void kernel_launch(void* const* d_in, const int* in_sizes, int n_in,
                              void* d_out, int out_size, void* d_ws, size_t ws_size,
                              hipStream_t stream) {
  const float* x    = (const float*)d_in[0];
  const float* W_ih = (const float*)d_in[1];
  const float* W_hh = (const float*)d_in[2];
  const float* b_ih = (const float*)d_in[3];
  const float* b_hh = (const float*)d_in[4];
  const float* W_fc = (const float*)d_in[5];
  const float* b_fc = (const float*)d_in[6];
  float* out = (float*)d_out;

  const size_t need = (size_t)B_SZ * T_SZ * 16 * sizeof(float);
  if (ws_size >= need) {
    float* xg = (float*)d_ws;
    hipLaunchKernelGGL(xgates_kernel, dim3(B_SZ * T_SZ / 256), dim3(256), 0, stream,
                       x, W_ih, b_ih, b_hh, xg);
    hipLaunchKernelGGL(lstm_scan, dim3(B_SZ * 4 / 64), dim3(64), 0, stream,
                       xg, W_hh, W_fc, b_fc, out);
  } else {
    hipLaunchKernelGGL(lstm_fused, dim3(B_SZ * 4 / 256), dim3(256), 0, stream,
                       x, W_ih, W_hh, b_ih, b_hh, W_fc, b_fc, out);
  }
}

// Round 3
// 85.626 us; speedup vs baseline: 1.5263x; 1.1559x over previous
//
#include <hip/hip_runtime.h>

#define B_SZ 4096
#define T_SZ 200
#define IN_SZ 34
// HIDDEN = 4, 4*H = 16 gates, gate order i,f,g,o (rows of W_ih/W_hh)

__device__ __forceinline__ float sigf(float x) {
    return 1.0f / (1.0f + __expf(-x));
}
__device__ __forceinline__ float tanh_f(float x) {
    return 2.0f / (1.0f + __expf(-2.0f * x)) - 1.0f;
}

// broadcast lane L (0..3) of each quad to all 4 lanes of the quad via DPP
__device__ __forceinline__ float quad_bcast0(float v) {
    int s = __float_as_int(v);
    return __int_as_float(__builtin_amdgcn_update_dpp(s, s, 0x00, 0xf, 0xf, true));
}
__device__ __forceinline__ float quad_bcast1(float v) {
    int s = __float_as_int(v);
    return __int_as_float(__builtin_amdgcn_update_dpp(s, s, 0x55, 0xf, 0xf, true));
}
__device__ __forceinline__ float quad_bcast2(float v) {
    int s = __float_as_int(v);
    return __int_as_float(__builtin_amdgcn_update_dpp(s, s, 0xAA, 0xf, 0xf, true));
}
__device__ __forceinline__ float quad_bcast3(float v) {
    int s = __float_as_int(v);
    return __int_as_float(__builtin_amdgcn_update_dpp(s, s, 0xFF, 0xf, 0xf, true));
}

typedef const __attribute__((address_space(1))) unsigned int* gas_t;
typedef __attribute__((address_space(3))) unsigned int* las_t;

// Phase 1: x_gates[row][j][gt] = dot(x[row], W_ih[gt*4+j]) + b_ih[g] + b_hh[g]
// Single-wave blocks (64 rows, 8704B LDS): no cross-wave barrier, high
// residency (~18 blocks/CU), global_load_lds width-16 coalesced staging.
__global__ __launch_bounds__(64) void xgates_kernel(
    const float* __restrict__ x, const float* __restrict__ W_ih,
    const float* __restrict__ b_ih, const float* __restrict__ b_hh,
    float* __restrict__ xg) {
  __shared__ float xs[64 * IN_SZ];  // 8704 B, exactly linear (no pad)
  int lane = threadIdx.x;
  // 64 rows * 34 floats = 544 float4. 8 full wave-iters + half iter.
  const float4* src = reinterpret_cast<const float4*>(x + (size_t)blockIdx.x * 64 * IN_SZ);
  char* ldsb = reinterpret_cast<char*>(xs);
  #pragma unroll
  for (int i = 0; i < 8; ++i) {
    __builtin_amdgcn_global_load_lds((gas_t)(src + i * 64 + lane),
                                     (las_t)(ldsb + i * 1024), 16, 0, 0);
  }
  if (lane < 32) {
    __builtin_amdgcn_global_load_lds((gas_t)(src + 512 + lane),
                                     (las_t)(ldsb + 8192), 16, 0, 0);
  }
  __syncthreads();  // single wave: just drains vmcnt, barrier is free

  float xr[IN_SZ];
  const float2* rp = reinterpret_cast<const float2*>(&xs[lane * IN_SZ]);
  #pragma unroll
  for (int k = 0; k < IN_SZ / 2; ++k) {
    float2 v = rp[k];
    xr[2 * k] = v.x;
    xr[2 * k + 1] = v.y;
  }
  float acc[16];
  #pragma unroll
  for (int g = 0; g < 16; ++g) acc[g] = b_ih[g] + b_hh[g];  // uniform s_loads
  #pragma unroll
  for (int k = 0; k < IN_SZ; ++k) {
    #pragma unroll
    for (int g = 0; g < 16; ++g)
      acc[g] = fmaf(xr[k], W_ih[g * IN_SZ + k], acc[g]);  // W uniform -> SGPR
  }
  // write [row][j=0..3][gt=i,f,g,o] as 4 float4s (64B contiguous per row)
  size_t row = (size_t)blockIdx.x * 64 + lane;
  float4* op = reinterpret_cast<float4*>(xg + row * 16);
  #pragma unroll
  for (int j = 0; j < 4; ++j)
    op[j] = make_float4(acc[j], acc[4 + j], acc[8 + j], acc[12 + j]);
}

// Phase 2: recurrent scan. 4 lanes per batch element, lane j owns h_j/c_j.
// Register double-buffered prefetch (U=10), DPP quad broadcasts for h.
#define U_SZ 10
__global__ __launch_bounds__(64) void lstm_scan(
    const float* __restrict__ xg, const float* __restrict__ W_hh,
    const float* __restrict__ W_fc, const float* __restrict__ b_fc,
    float* __restrict__ out) {
  int tid = blockIdx.x * 64 + threadIdx.x;
  int b = tid >> 2;
  int j = tid & 3;
  float Wi[4], Wf[4], Wg[4], Wo[4];
  #pragma unroll
  for (int k = 0; k < 4; ++k) {
    Wi[k] = W_hh[(0 + j) * 4 + k];
    Wf[k] = W_hh[(4 + j) * 4 + k];
    Wg[k] = W_hh[(8 + j) * 4 + k];
    Wo[k] = W_hh[(12 + j) * 4 + k];
  }
  float h[4] = {0.f, 0.f, 0.f, 0.f};
  float c = 0.f;

  auto step = [&](float4 g4) {
    float pi = g4.x, pf = g4.y, pg = g4.z, po = g4.w;
    #pragma unroll
    for (int k = 0; k < 4; ++k) {
      pi = fmaf(Wi[k], h[k], pi);
      pf = fmaf(Wf[k], h[k], pf);
      pg = fmaf(Wg[k], h[k], pg);
      po = fmaf(Wo[k], h[k], po);
    }
    float iv = sigf(pi);
    float fv = sigf(pf);
    float gv = tanh_f(pg);
    float ov = sigf(po);
    c = fmaf(fv, c, iv * gv);
    float hj = ov * tanh_f(c);
    h[0] = quad_bcast0(hj);
    h[1] = quad_bcast1(hj);
    h[2] = quad_bcast2(hj);
    h[3] = quad_bcast3(hj);
  };

  const float4* xp = reinterpret_cast<const float4*>(xg) + (size_t)b * (T_SZ * 4) + j;
  float4 bufA[U_SZ], bufB[U_SZ];
  #pragma unroll
  for (int u = 0; u < U_SZ; ++u) bufA[u] = xp[4 * u];

  // T=200 = 20 blocks of 10; ping-pong pairs
  #pragma unroll 1
  for (int blk = 0; blk < 20; blk += 2) {
    const float4* p1 = xp + (size_t)(blk + 1) * (4 * U_SZ);
    #pragma unroll
    for (int u = 0; u < U_SZ; ++u) bufB[u] = p1[4 * u];
    #pragma unroll
    for (int u = 0; u < U_SZ; ++u) step(bufA[u]);
    if (blk + 2 < 20) {
      const float4* p2 = xp + (size_t)(blk + 2) * (4 * U_SZ);
      #pragma unroll
      for (int u = 0; u < U_SZ; ++u) bufA[u] = p2[4 * u];
    }
    #pragma unroll
    for (int u = 0; u < U_SZ; ++u) step(bufB[u]);
  }

  if (j < 3) {
    float acc = b_fc[j];
    #pragma unroll
    for (int k = 0; k < 4; ++k) acc = fmaf(W_fc[j * 4 + k], h[k], acc);
    out[b * 3 + j] = acc;
  }
}

// Fallback (only if workspace is too small): fused single kernel, W_ih in LDS.
__global__ __launch_bounds__(256) void lstm_fused(
    const float* __restrict__ x, const float* __restrict__ W_ih,
    const float* __restrict__ W_hh, const float* __restrict__ b_ih,
    const float* __restrict__ b_hh, const float* __restrict__ W_fc,
    const float* __restrict__ b_fc, float* __restrict__ out) {
  __shared__ float Ws[16 * IN_SZ];
  for (int i = threadIdx.x; i < 16 * IN_SZ; i += 256) Ws[i] = W_ih[i];
  __syncthreads();
  int tid = blockIdx.x * 256 + threadIdx.x;
  int b = tid >> 2;
  int j = tid & 3;
  float bi = b_ih[0 + j] + b_hh[0 + j];
  float bf = b_ih[4 + j] + b_hh[4 + j];
  float bg = b_ih[8 + j] + b_hh[8 + j];
  float bo = b_ih[12 + j] + b_hh[12 + j];
  float Wi[4], Wf[4], Wg[4], Wo[4];
  #pragma unroll
  for (int k = 0; k < 4; ++k) {
    Wi[k] = W_hh[(0 + j) * 4 + k];
    Wf[k] = W_hh[(4 + j) * 4 + k];
    Wg[k] = W_hh[(8 + j) * 4 + k];
    Wo[k] = W_hh[(12 + j) * 4 + k];
  }
  float h[4] = {0.f, 0.f, 0.f, 0.f};
  float c = 0.f;
  const float2* xp = reinterpret_cast<const float2*>(x + (size_t)b * T_SZ * IN_SZ);
  int lbase = (threadIdx.x & 63) & ~3;
  for (int t = 0; t < T_SZ; ++t) {
    float xr[IN_SZ];
    #pragma unroll
    for (int k = 0; k < IN_SZ / 2; ++k) {
      float2 v = xp[(size_t)t * (IN_SZ / 2) + k];
      xr[2 * k] = v.x;
      xr[2 * k + 1] = v.y;
    }
    float pi = bi, pf = bf, pg = bg, po = bo;
    #pragma unroll
    for (int k = 0; k < IN_SZ; ++k) {
      pi = fmaf(xr[k], Ws[(0 + j) * IN_SZ + k], pi);
      pf = fmaf(xr[k], Ws[(4 + j) * IN_SZ + k], pf);
      pg = fmaf(xr[k], Ws[(8 + j) * IN_SZ + k], pg);
      po = fmaf(xr[k], Ws[(12 + j) * IN_SZ + k], po);
    }
    #pragma unroll
    for (int k = 0; k < 4; ++k) {
      pi = fmaf(Wi[k], h[k], pi);
      pf = fmaf(Wf[k], h[k], pf);
      pg = fmaf(Wg[k], h[k], pg);
      po = fmaf(Wo[k], h[k], po);
    }
    float iv = sigf(pi);
    float fv = sigf(pf);
    float gv = tanh_f(pg);
    float ov = sigf(po);
    c = fmaf(fv, c, iv * gv);
    float hj = ov * tanh_f(c);
    h[0] = __shfl(hj, lbase + 0);
    h[1] = __shfl(hj, lbase + 1);
    h[2] = __shfl(hj, lbase + 2);
    h[3] = __shfl(hj, lbase + 3);
  }
  if (j < 3) {
    float acc = b_fc[j];
    #pragma unroll
    for (int k = 0; k < 4; ++k) acc = fmaf(W_fc[j * 4 + k], h[k], acc);
    out[b * 3 + j] = acc;
  }
}

extern "C" void kernel_launch(void* const* d_in, const int* in_sizes, int n_in,
                              void* d_out, int out_size, void* d_ws, size_t ws_size,
                              hipStream_t stream) {
  const float* x    = (const float*)d_in[0];
  const float* W_ih = (const float*)d_in[1];
  const float* W_hh = (const float*)d_in[2];
  const float* b_ih = (const float*)d_in[3];
  const float* b_hh = (const float*)d_in[4];
  const float* W_fc = (const float*)d_in[5];
  const float* b_fc = (const float*)d_in[6];
  float* out = (float*)d_out;

  const size_t need = (size_t)B_SZ * T_SZ * 16 * sizeof(float);
  if (ws_size >= need) {
    float* xg = (float*)d_ws;
    hipLaunchKernelGGL(xgates_kernel, dim3(B_SZ * T_SZ / 64), dim3(64), 0, stream,
                       x, W_ih, b_ih, b_hh, xg);
    hipLaunchKernelGGL(lstm_scan, dim3(B_SZ * 4 / 64), dim3(64), 0, stream,
                       xg, W_hh, W_fc, b_fc, out);
  } else {
    hipLaunchKernelGGL(lstm_fused, dim3(B_SZ * 4 / 256), dim3(256), 0, stream,
                       x, W_ih, W_hh, b_ih, b_hh, W_fc, b_fc, out);
  }
}